// Round 7
// baseline (1053.372 us; speedup 1.0000x reference)
//
#include <hip/hip_runtime.h>
#include <math.h>

#define ISQ2 0.70710678118654752440f

typedef __attribute__((ext_vector_type(8))) short bfrag8;
typedef __attribute__((ext_vector_type(4))) float f32x4;

static __device__ __constant__ float H0c[13] = {
    -0.0017578f, 0.0f, 0.0222656f, -0.046875f, -0.0482422f, 0.296875f,
    0.5554688f, 0.296875f, -0.0482422f, -0.046875f, 0.0222656f, 0.0f, -0.0017578f};
static __device__ __constant__ float H1c[19] = {
    -7.06e-05f, 0.0f, 0.0013419f, -0.0018834f, -0.0071568f, 0.023856f,
    0.0556431f, -0.0516881f, -0.2997576f, 0.5594308f, -0.2997576f, -0.0516881f,
    0.0556431f, 0.023856f, -0.0071568f, -0.0018834f, 0.0013419f, 0.0f, -7.06e-05f};

__device__ __forceinline__ int refl32(int i) {
    if (i < 0) i = -1 - i;
    if (i > 31) i = 63 - i;
    return i;
}

__device__ __forceinline__ float gelu_exact(float x) {
    return 0.5f * x * (1.0f + erff(x * ISQ2));
}

__device__ __forceinline__ float bf2f(unsigned short u) {
    union { unsigned int i; float f; } v;
    v.i = ((unsigned int)u) << 16;
    return v.f;
}

__device__ __forceinline__ float bflo(unsigned int u) {
    union { unsigned int i; float f; } v;
    v.i = u << 16;
    return v.f;
}
__device__ __forceinline__ float bfhi(unsigned int u) {
    union { unsigned int i; float f; } v;
    v.i = u & 0xFFFF0000u;
    return v.f;
}

__device__ __forceinline__ unsigned short f2bf(float a) {
    union { float f; unsigned int i; } ua;
    ua.f = a;
    unsigned int r = ua.i + 0x7FFF + ((ua.i >> 16) & 1);
    return (unsigned short)(r >> 16);
}

// ---------------- K1: LN1 + transpose (B,N,C)->(B,C,32,32) ----------------
__global__ __launch_bounds__(256) void k_ln1_t(const float* __restrict__ x,
                                               const float* __restrict__ g,
                                               const float* __restrict__ be,
                                               float* __restrict__ A) {
    __shared__ float sx[64][65];
    __shared__ float rs[64][4], rq[64][4];
    __shared__ float sm[64], sv[64];
    int b = blockIdx.x >> 4;
    int n0 = (blockIdx.x & 15) << 6;
    int tid = threadIdx.x;
    const float* xp = x + ((size_t)b * 1024 + n0) * 64;
#pragma unroll
    for (int rep = 0; rep < 16; ++rep) {
        int idx = rep * 256 + tid;
        sx[idx >> 6][idx & 63] = xp[idx];
    }
    __syncthreads();
    {
        int i = tid >> 2, q = tid & 3;
        float s = 0.f, ss = 0.f;
#pragma unroll
        for (int d = 0; d < 16; ++d) {
            float v = sx[i][q * 16 + d];
            s += v; ss += v * v;
        }
        rs[i][q] = s; rq[i][q] = ss;
    }
    __syncthreads();
    if (tid < 64) {
        float s = rs[tid][0] + rs[tid][1] + rs[tid][2] + rs[tid][3];
        float ss = rq[tid][0] + rq[tid][1] + rq[tid][2] + rq[tid][3];
        float m = s * (1.f / 64.f);
        float v = ss * (1.f / 64.f) - m * m;
        sm[tid] = m;
        sv[tid] = rsqrtf(v + 1e-5f);
    }
    __syncthreads();
#pragma unroll
    for (int rep = 0; rep < 16; ++rep) {
        int idx = rep * 256 + tid;
        int c = idx >> 6, i = idx & 63;
        float val = (sx[i][c] - sm[i]) * sv[i] * g[c] + be[c];
        A[((size_t)(b * 64 + c)) * 1024 + n0 + i] = val;
    }
}

// ---------------- K2: forward DTCWT per (b,c) image ----------------
__device__ __forceinline__ float col19(const float (*arr)[33], int h, int w) {
    float s = 0.f;
#pragma unroll
    for (int k = 0; k < 19; ++k) s += H1c[k] * arr[refl32(h + k - 9)][w];
    return s;
}
__device__ __forceinline__ float col13(const float (*arr)[33], int h, int w) {
    float s = 0.f;
#pragma unroll
    for (int k = 0; k < 13; ++k) s += H0c[k] * arr[refl32(h + k - 6)][w];
    return s;
}

__global__ __launch_bounds__(256) void k_fwd(const float* __restrict__ A,
                                             const float* __restrict__ wll,
                                             float* __restrict__ LL,
                                             float* __restrict__ HSr,
                                             float* __restrict__ HSi) {
    __shared__ float sx[32][33], slo[32][33], shi[32][33];
    int bc = blockIdx.x;
    int c = bc & 63;
    int tid = threadIdx.x;
    const float* ap = A + (size_t)bc * 1024;
#pragma unroll
    for (int r = 0; r < 4; ++r) {
        int p = r * 256 + tid;
        sx[p >> 5][p & 31] = ap[p];
    }
    __syncthreads();
#pragma unroll
    for (int r = 0; r < 4; ++r) {
        int p = r * 256 + tid;
        int h = p >> 5, w = p & 31;
        float lo = 0.f, hi = 0.f;
#pragma unroll
        for (int k = 0; k < 13; ++k) lo += H0c[k] * sx[h][refl32(w + k - 6)];
#pragma unroll
        for (int k = 0; k < 19; ++k) hi += H1c[k] * sx[h][refl32(w + k - 9)];
        slo[h][w] = lo;
        shi[h][w] = hi;
    }
    __syncthreads();
#pragma unroll
    for (int r = 0; r < 4; ++r) {
        int p = r * 256 + tid;
        int h = p >> 5, w = p & 31;
        float acc = 0.f;
#pragma unroll
        for (int k = 0; k < 13; ++k) acc += H0c[k] * slo[refl32(h + k - 6)][w];
        LL[(size_t)bc * 1024 + p] = acc * wll[c * 1024 + p];
    }
    {
        int p = tid;
        int i = p >> 4, j = p & 15;
        int h0 = 2 * i, w0 = 2 * j;
        size_t base = (size_t)bc * 1536 + p;
        float a, bb, cc, dd;
        a = col19(slo, h0, w0); bb = col19(slo, h0, w0 + 1);
        cc = col19(slo, h0 + 1, w0); dd = col19(slo, h0 + 1, w0 + 1);
        HSr[base + 0 * 256] = (a - dd) * ISQ2; HSi[base + 0 * 256] = (bb + cc) * ISQ2;
        HSr[base + 5 * 256] = (a + dd) * ISQ2; HSi[base + 5 * 256] = (bb - cc) * ISQ2;
        a = col19(shi, h0, w0); bb = col19(shi, h0, w0 + 1);
        cc = col19(shi, h0 + 1, w0); dd = col19(shi, h0 + 1, w0 + 1);
        HSr[base + 1 * 256] = (a - dd) * ISQ2; HSi[base + 1 * 256] = (bb + cc) * ISQ2;
        HSr[base + 4 * 256] = (a + dd) * ISQ2; HSi[base + 4 * 256] = (bb - cc) * ISQ2;
        a = col13(shi, h0, w0); bb = col13(shi, h0, w0 + 1);
        cc = col13(shi, h0 + 1, w0); dd = col13(shi, h0 + 1, w0 + 1);
        HSr[base + 2 * 256] = (a - dd) * ISQ2; HSi[base + 2 * 256] = (bb + cc) * ISQ2;
        HSr[base + 3 * 256] = (a + dd) * ISQ2; HSi[base + 3 * 256] = (bb - cc) * ISQ2;
    }
}

// ---------------- K3: complex block-diagonal MLP (token-per-lane, scalar weights) --
// launch_bounds(256,4): allow ~128 VGPR so the 64-float live set doesn't spill.
__global__ __launch_bounds__(256, 4) void k_mlp(float* __restrict__ HSr,
                                                float* __restrict__ HSi,
                                                const float* __restrict__ w1,
                                                const float* __restrict__ w2,
                                                const float* __restrict__ b1,
                                                const float* __restrict__ b2) {
    int tid = threadIdx.x;
    int b = blockIdx.x / 6;
    int o = blockIdx.x - b * 6;
    size_t base = ((size_t)b * 384 + o) * 256 + tid;  // c=0 element for this lane
#pragma unroll 1
    for (int q = 0; q < 4; ++q) {
        float xr[16], xi[16];
#pragma unroll
        for (int d = 0; d < 16; ++d) {
            size_t gi = base + (size_t)(q * 16 + d) * 1536;
            xr[d] = HSr[gi];
            xi[d] = HSi[gi];
        }
        float r1[16], i1[16];
#pragma unroll 4
        for (int k = 0; k < 16; ++k) {
            float ar = b1[q * 16 + k];
            float ai = b1[64 + q * 16 + k];
#pragma unroll
            for (int d = 0; d < 16; ++d) {
                float wr = w1[q * 256 + d * 16 + k];
                float wi = w1[1024 + q * 256 + d * 16 + k];
                ar += xr[d] * wr - xi[d] * wi;
                ai += xr[d] * wi + xi[d] * wr;
            }
            r1[k] = fmaxf(ar, 0.f);
            i1[k] = fmaxf(ai, 0.f);
        }
#pragma unroll 4
        for (int k = 0; k < 16; ++k) {
            float ar = b2[q * 16 + k];
            float ai = b2[64 + q * 16 + k];
#pragma unroll
            for (int d = 0; d < 16; ++d) {
                float wr = w2[q * 256 + d * 16 + k];
                float wi = w2[1024 + q * 256 + d * 16 + k];
                ar += r1[d] * wr - i1[d] * wi;
                ai += r1[d] * wi + i1[d] * wr;
            }
            size_t gi = base + (size_t)(q * 16 + k) * 1536;
            HSr[gi] = ar;
            HSi[gi] = ai;
        }
    }
}

// ---------------- K4: inverse DTCWT per (b,c) -> Y (B,C,N) ----------------
__global__ __launch_bounds__(256) void k_inv(const float* __restrict__ LL,
                                             const float* __restrict__ HSr,
                                             const float* __restrict__ HSi,
                                             float* __restrict__ Y) {
    __shared__ float sll[32][33], slh[32][33], shl[32][33], shh[32][33];
    __shared__ float slo[32][33], shi[32][33];
    int bc = blockIdx.x;
    int tid = threadIdx.x;
    const float* lp = LL + (size_t)bc * 1024;
#pragma unroll
    for (int r = 0; r < 4; ++r) {
        int p = r * 256 + tid;
        sll[p >> 5][p & 31] = lp[p];
    }
    {
        int p = tid;
        int i = p >> 4, j = p & 15;
        int h0 = 2 * i, w0 = 2 * j;
        size_t base = (size_t)bc * 1536 + p;
        float o0r = HSr[base + 0 * 256], o0i = HSi[base + 0 * 256];
        float o1r = HSr[base + 1 * 256], o1i = HSi[base + 1 * 256];
        float o2r = HSr[base + 2 * 256], o2i = HSi[base + 2 * 256];
        float o3r = HSr[base + 3 * 256], o3i = HSi[base + 3 * 256];
        float o4r = HSr[base + 4 * 256], o4i = HSi[base + 4 * 256];
        float o5r = HSr[base + 5 * 256], o5i = HSi[base + 5 * 256];
        slh[h0][w0] = (o0r + o5r) * ISQ2;
        slh[h0][w0 + 1] = (o0i + o5i) * ISQ2;
        slh[h0 + 1][w0] = (o0i - o5i) * ISQ2;
        slh[h0 + 1][w0 + 1] = (o5r - o0r) * ISQ2;
        shl[h0][w0] = (o2r + o3r) * ISQ2;
        shl[h0][w0 + 1] = (o2i + o3i) * ISQ2;
        shl[h0 + 1][w0] = (o2i - o3i) * ISQ2;
        shl[h0 + 1][w0 + 1] = (o3r - o2r) * ISQ2;
        shh[h0][w0] = (o1r + o4r) * ISQ2;
        shh[h0][w0 + 1] = (o1i + o4i) * ISQ2;
        shh[h0 + 1][w0] = (o1i - o4i) * ISQ2;
        shh[h0 + 1][w0 + 1] = (o4r - o1r) * ISQ2;
    }
    __syncthreads();
#pragma unroll
    for (int r = 0; r < 4; ++r) {
        int p = r * 256 + tid;
        int h = p >> 5, w = p & 31;
        float lo = 0.f, hi = 0.f;
#pragma unroll
        for (int k = 0; k < 19; ++k) {
            float g0 = (k & 1) ? H1c[k] : -H1c[k];
            int hh2 = refl32(h + k - 9);
            lo += g0 * sll[hh2][w];
            hi += g0 * shl[hh2][w];
        }
#pragma unroll
        for (int k = 0; k < 13; ++k) {
            float g1 = (k & 1) ? H0c[k] : -H0c[k];
            int hh2 = refl32(h + k - 6);
            lo += g1 * slh[hh2][w];
            hi += g1 * shh[hh2][w];
        }
        slo[h][w] = lo;
        shi[h][w] = hi;
    }
    __syncthreads();
#pragma unroll
    for (int r = 0; r < 4; ++r) {
        int p = r * 256 + tid;
        int h = p >> 5, w = p & 31;
        float y = 0.f;
#pragma unroll
        for (int k = 0; k < 19; ++k) {
            float g0 = (k & 1) ? H1c[k] : -H1c[k];
            y += g0 * slo[h][refl32(w + k - 9)];
        }
#pragma unroll
        for (int k = 0; k < 13; ++k) {
            float g1 = (k & 1) ? H0c[k] : -H0c[k];
            y += g1 * shi[h][refl32(w + k - 6)];
        }
        Y[(size_t)bc * 1024 + p] = y;
    }
}

// ---------------- K4b: X1 = x + Y^T -> d_out (B,N,C) ----------------
__global__ __launch_bounds__(256) void k_addt(const float* __restrict__ Y,
                                              const float* __restrict__ x,
                                              float* __restrict__ out) {
    __shared__ float sy[64][65];
    int b = blockIdx.x >> 4;
    int n0 = (blockIdx.x & 15) << 6;
    int tid = threadIdx.x;
#pragma unroll
    for (int rep = 0; rep < 16; ++rep) {
        int idx = rep * 256 + tid;
        int c = idx >> 6, i = idx & 63;
        sy[c][i] = Y[((size_t)(b * 64 + c)) * 1024 + n0 + i];
    }
    __syncthreads();
#pragma unroll
    for (int rep = 0; rep < 16; ++rep) {
        int idx = rep * 256 + tid;
        int i = idx >> 6, c = idx & 63;
        size_t gi = ((size_t)b * 1024 + n0 + i) * 64 + c;
        out[gi] = x[gi] + sy[c][i];
    }
}

// ---------------- K5: LN2 + lin1 + GELU -> H1 bf16 chunk-major ----------------
// H1 layout: (b, k0=hid/32, h, w, hid%32)
__global__ __launch_bounds__(256) void k_leff1(const float* __restrict__ X1,
                                               const float* __restrict__ g2,
                                               const float* __restrict__ be2,
                                               const float* __restrict__ W1,
                                               const float* __restrict__ B1,
                                               unsigned short* __restrict__ H1b) {
    __shared__ float xs[64][65];
    __shared__ float w1s[64][128];
    int tid = threadIdx.x;
    size_t tok0 = (size_t)blockIdx.x * 64;
    int bimg = blockIdx.x >> 4;
    int hw0 = (blockIdx.x & 15) << 6;
    {
        int tok = tid >> 2, part = tid & 3;
        const float4* xp = (const float4*)(X1 + (tok0 + tok) * 64 + part * 16);
        float4 v0 = xp[0], v1 = xp[1], v2 = xp[2], v3 = xp[3];
        float s = v0.x + v0.y + v0.z + v0.w + v1.x + v1.y + v1.z + v1.w +
                  v2.x + v2.y + v2.z + v2.w + v3.x + v3.y + v3.z + v3.w;
        float ss = v0.x * v0.x + v0.y * v0.y + v0.z * v0.z + v0.w * v0.w +
                   v1.x * v1.x + v1.y * v1.y + v1.z * v1.z + v1.w * v1.w +
                   v2.x * v2.x + v2.y * v2.y + v2.z * v2.z + v2.w * v2.w +
                   v3.x * v3.x + v3.y * v3.y + v3.z * v3.z + v3.w * v3.w;
        s += __shfl_xor(s, 1, 64);
        ss += __shfl_xor(ss, 1, 64);
        s += __shfl_xor(s, 2, 64);
        ss += __shfl_xor(ss, 2, 64);
        float m = s * (1.f / 64.f);
        float var = ss * (1.f / 64.f) - m * m;
        float rstd = rsqrtf(var + 1e-5f);
        float vv[16] = {v0.x, v0.y, v0.z, v0.w, v1.x, v1.y, v1.z, v1.w,
                        v2.x, v2.y, v2.z, v2.w, v3.x, v3.y, v3.z, v3.w};
#pragma unroll
        for (int i = 0; i < 16; ++i) {
            int d = part * 16 + i;
            xs[tok][d] = (vv[i] - m) * rstd * g2[d] + be2[d];
        }
    }
    int tg = tid >> 5, cg = tid & 31;
#pragma unroll 1
    for (int half = 0; half < 2; ++half) {
        __syncthreads();
        for (int i = 0; i < 32; ++i) {
            int idx = i * 256 + tid;
            int d = idx >> 7, c = idx & 127;
            w1s[d][c] = W1[d * 256 + half * 128 + c];
        }
        __syncthreads();
        float acc[8][4];
#pragma unroll
        for (int t = 0; t < 8; ++t)
#pragma unroll
            for (int j = 0; j < 4; ++j)
                acc[t][j] = B1[half * 128 + j * 32 + cg];
#pragma unroll 2
        for (int d = 0; d < 64; ++d) {
            float w0 = w1s[d][cg];
            float w1v = w1s[d][32 + cg];
            float w2v = w1s[d][64 + cg];
            float w3v = w1s[d][96 + cg];
#pragma unroll
            for (int t = 0; t < 8; ++t) {
                float xv = xs[tg * 8 + t][d];
                acc[t][0] += xv * w0;
                acc[t][1] += xv * w1v;
                acc[t][2] += xv * w2v;
                acc[t][3] += xv * w3v;
            }
        }
#pragma unroll
        for (int t = 0; t < 8; ++t) {
            int hw = hw0 + tg * 8 + t;
#pragma unroll
            for (int j = 0; j < 4; ++j) {
                size_t gi = (((size_t)bimg * 8 + half * 4 + j) * 1024 + hw) * 32 + cg;
                H1b[gi] = f2bf(gelu_exact(acc[t][j]));
            }
        }
    }
}

// ---------------- K5b: prep DWT (tap-major) + W2T bf16 ----------------
__global__ __launch_bounds__(256) void k_prep(const float* __restrict__ DW,
                                              const float* __restrict__ W2,
                                              float* __restrict__ DWT,
                                              unsigned short* __restrict__ W2T) {
    int gid = blockIdx.x * 256 + threadIdx.x;
    int stride = gridDim.x * 256;
    for (int i = gid; i < 2304; i += stride) {
        int hid = i / 9, t = i - hid * 9;
        DWT[t * 256 + hid] = DW[i];
    }
    for (int i = gid; i < 16384; i += stride) {
        int n = i >> 8, k = i & 255;
        W2T[i] = f2bf(W2[k * 64 + n]);
    }
}

// ---------------- K6: fused dwconv3x3+GELU+lin2(MFMA)+bias+residual ----------
// Batched tap loads (9 outstanding) before unpack/FMA for memory-level parallelism.
__global__ __launch_bounds__(256, 4) void k_leff2m(const unsigned short* __restrict__ H1b,
                                                   const float* __restrict__ DWT,
                                                   const float* __restrict__ DB,
                                                   const unsigned short* __restrict__ W2T,
                                                   const float* __restrict__ B2,
                                                   float* __restrict__ out) {
    int tid = threadIdx.x;
    int wid = tid >> 6, lane = tid & 63;
    int mt = blockIdx.x * 4 + wid;   // 0..16383
    int b = mt >> 6;
    int rem = mt & 63;
    int h = rem >> 1;                // image row (wave-uniform)
    int w0 = (rem & 1) << 4;         // 0 or 16
    int lr = lane & 15;              // A-row (token) / C-col index
    int kg = lane >> 4;              // k-group 0..3
    int wA = w0 + lr;                // this lane's token w

    f32x4 acc[4];
#pragma unroll
    for (int n = 0; n < 4; ++n) acc[n] = (f32x4){0.f, 0.f, 0.f, 0.f};

#pragma unroll 1
    for (int k0 = 0; k0 < 8; ++k0) {
        int hid0 = k0 * 32 + kg * 8;
        size_t cbase = ((size_t)b * 8 + k0) * 1024;
        // ---- batch-issue all 9 tap loads ----
        uint4 tv[9];
#pragma unroll
        for (int t = 0; t < 9; ++t) tv[t] = make_uint4(0u, 0u, 0u, 0u);
#pragma unroll
        for (int dr = -1; dr <= 1; ++dr) {
            int hr = h + dr;
            if (hr < 0 || hr > 31) continue;   // wave-uniform
#pragma unroll
            for (int dc = -1; dc <= 1; ++dc) {
                int wc = wA + dc;
                if (wc < 0 || wc > 31) continue;  // edge lanes only
                tv[(dr + 1) * 3 + (dc + 1)] =
                    *(const uint4*)(H1b + ((cbase + (size_t)hr * 32 + wc) << 5) + kg * 8);
            }
        }
        // ---- unpack + conv FMA ----
        const f32x4* dbp = (const f32x4*)(DB + hid0);
        f32x4 d0 = dbp[0], d1 = dbp[1];
        float cv[8] = {d0.x, d0.y, d0.z, d0.w, d1.x, d1.y, d1.z, d1.w};
#pragma unroll
        for (int t = 0; t < 9; ++t) {
            uint4 v = tv[t];
            const f32x4* wp = (const f32x4*)(DWT + t * 256 + hid0);
            f32x4 q0 = wp[0], q1 = wp[1];
            cv[0] += bflo(v.x) * q0.x;
            cv[1] += bfhi(v.x) * q0.y;
            cv[2] += bflo(v.y) * q0.z;
            cv[3] += bfhi(v.y) * q0.w;
            cv[4] += bflo(v.z) * q1.x;
            cv[5] += bfhi(v.z) * q1.y;
            cv[6] += bflo(v.w) * q1.z;
            cv[7] += bfhi(v.w) * q1.w;
        }
        bfrag8 a;
#pragma unroll
        for (int e = 0; e < 8; ++e) a[e] = (short)f2bf(gelu_exact(cv[e]));
#pragma unroll
        for (int n = 0; n < 4; ++n) {
            bfrag8 bf = *(const bfrag8*)(W2T + ((size_t)(n * 16 + lr) * 256 + k0 * 32 + kg * 8));
            acc[n] = __builtin_amdgcn_mfma_f32_16x16x32_bf16(a, bf, acc[n], 0, 0, 0);
        }
    }
    // epilogue: C layout col=lane&15, row=(lane>>4)*4+reg
    size_t obase = (size_t)b * 1024 + (size_t)h * 32;
#pragma unroll
    for (int n = 0; n < 4; ++n) {
        int c = n * 16 + lr;
        float b2v = B2[c];
#pragma unroll
        for (int reg = 0; reg < 4; ++reg) {
            int rowTok = w0 + kg * 4 + reg;
            size_t gi = (obase + rowTok) * 64 + c;
            out[gi] += acc[n][reg] + b2v;
        }
    }
}

extern "C" void kernel_launch(void* const* d_in, const int* in_sizes, int n_in,
                              void* d_out, int out_size, void* d_ws, size_t ws_size,
                              hipStream_t stream) {
    const float* x = (const float*)d_in[0];
    const float* ln1_g = (const float*)d_in[1];
    const float* ln1_b = (const float*)d_in[2];
    const float* w_ll = (const float*)d_in[3];
    const float* w1 = (const float*)d_in[4];
    const float* w2 = (const float*)d_in[5];
    const float* b1 = (const float*)d_in[6];
    const float* b2 = (const float*)d_in[7];
    const float* ln2_g = (const float*)d_in[8];
    const float* ln2_b = (const float*)d_in[9];
    const float* lin1_w = (const float*)d_in[10];
    const float* lin1_b = (const float*)d_in[11];
    const float* dw_w = (const float*)d_in[12];
    const float* dw_b = (const float*)d_in[13];
    const float* lin2_w = (const float*)d_in[14];
    const float* lin2_b = (const float*)d_in[15];
    float* out = (float*)d_out;
    char* ws = (char*)d_ws;

    float* A = (float*)ws;
    float* HSr = (float*)(ws + 67108864);
    float* HSi = (float*)(ws + 167772160);
    float* LL = out;
    float* Y = A;
    unsigned short* H1b = (unsigned short*)ws;          // [0, 134.2MB)
    float* DWT = (float*)(ws + 167772160);              // reuses dead HSi
    unsigned short* W2T = (unsigned short*)(ws + 167772160 + 16384);

    k_ln1_t<<<dim3(4096), dim3(256), 0, stream>>>(x, ln1_g, ln1_b, A);
    k_fwd<<<dim3(16384), dim3(256), 0, stream>>>(A, w_ll, LL, HSr, HSi);
    k_mlp<<<dim3(1536), dim3(256), 0, stream>>>(HSr, HSi, w1, w2, b1, b2);
    k_inv<<<dim3(16384), dim3(256), 0, stream>>>(LL, HSr, HSi, Y);
    k_addt<<<dim3(4096), dim3(256), 0, stream>>>(Y, x, out);
    k_prep<<<dim3(72), dim3(256), 0, stream>>>(dw_w, lin2_w, DWT, W2T);
    k_leff1<<<dim3(4096), dim3(256), 0, stream>>>(out, ln2_g, ln2_b, lin1_w, lin1_b, H1b);
    k_leff2m<<<dim3(4096), dim3(256), 0, stream>>>(H1b, DWT, dw_b, W2T, b2, out);
}

// Round 8
// 824.744 us; speedup vs baseline: 1.2772x; 1.2772x over previous
//
#include <hip/hip_runtime.h>
#include <math.h>

#define ISQ2 0.70710678118654752440f

typedef __attribute__((ext_vector_type(8))) short bfrag8;
typedef __attribute__((ext_vector_type(4))) float f32x4;

static __device__ __constant__ float H0c[13] = {
    -0.0017578f, 0.0f, 0.0222656f, -0.046875f, -0.0482422f, 0.296875f,
    0.5554688f, 0.296875f, -0.0482422f, -0.046875f, 0.0222656f, 0.0f, -0.0017578f};
static __device__ __constant__ float H1c[19] = {
    -7.06e-05f, 0.0f, 0.0013419f, -0.0018834f, -0.0071568f, 0.023856f,
    0.0556431f, -0.0516881f, -0.2997576f, 0.5594308f, -0.2997576f, -0.0516881f,
    0.0556431f, 0.023856f, -0.0071568f, -0.0018834f, 0.0013419f, 0.0f, -7.06e-05f};

__device__ __forceinline__ int refl32(int i) {
    if (i < 0) i = -1 - i;
    if (i > 31) i = 63 - i;
    return i;
}

__device__ __forceinline__ float gelu_exact(float x) {
    return 0.5f * x * (1.0f + erff(x * ISQ2));
}

__device__ __forceinline__ float bf2f(unsigned short u) {
    union { unsigned int i; float f; } v;
    v.i = ((unsigned int)u) << 16;
    return v.f;
}

__device__ __forceinline__ float bflo(unsigned int u) {
    union { unsigned int i; float f; } v;
    v.i = u << 16;
    return v.f;
}
__device__ __forceinline__ float bfhi(unsigned int u) {
    union { unsigned int i; float f; } v;
    v.i = u & 0xFFFF0000u;
    return v.f;
}

__device__ __forceinline__ unsigned short f2bf(float a) {
    union { float f; unsigned int i; } ua;
    ua.f = a;
    unsigned int r = ua.i + 0x7FFF + ((ua.i >> 16) & 1);
    return (unsigned short)(r >> 16);
}

// ---------------- K1: LN1 + transpose (B,N,C)->(B,C,32,32) ----------------
__global__ __launch_bounds__(256) void k_ln1_t(const float* __restrict__ x,
                                               const float* __restrict__ g,
                                               const float* __restrict__ be,
                                               float* __restrict__ A) {
    __shared__ float sx[64][65];
    __shared__ float rs[64][4], rq[64][4];
    __shared__ float sm[64], sv[64];
    int b = blockIdx.x >> 4;
    int n0 = (blockIdx.x & 15) << 6;
    int tid = threadIdx.x;
    const float* xp = x + ((size_t)b * 1024 + n0) * 64;
#pragma unroll
    for (int rep = 0; rep < 16; ++rep) {
        int idx = rep * 256 + tid;
        sx[idx >> 6][idx & 63] = xp[idx];
    }
    __syncthreads();
    {
        int i = tid >> 2, q = tid & 3;
        float s = 0.f, ss = 0.f;
#pragma unroll
        for (int d = 0; d < 16; ++d) {
            float v = sx[i][q * 16 + d];
            s += v; ss += v * v;
        }
        rs[i][q] = s; rq[i][q] = ss;
    }
    __syncthreads();
    if (tid < 64) {
        float s = rs[tid][0] + rs[tid][1] + rs[tid][2] + rs[tid][3];
        float ss = rq[tid][0] + rq[tid][1] + rq[tid][2] + rq[tid][3];
        float m = s * (1.f / 64.f);
        float v = ss * (1.f / 64.f) - m * m;
        sm[tid] = m;
        sv[tid] = rsqrtf(v + 1e-5f);
    }
    __syncthreads();
#pragma unroll
    for (int rep = 0; rep < 16; ++rep) {
        int idx = rep * 256 + tid;
        int c = idx >> 6, i = idx & 63;
        float val = (sx[i][c] - sm[i]) * sv[i] * g[c] + be[c];
        A[((size_t)(b * 64 + c)) * 1024 + n0 + i] = val;
    }
}

// ------- padded-column helpers: arr rows are pre-mirrored (row r stores h=r-9) ----
__device__ __forceinline__ float colp19(const float (*arr)[33], int h, int w) {
    float s = 0.f;
#pragma unroll
    for (int k = 0; k < 19; ++k) s += H1c[k] * arr[h + k][w];
    return s;
}
__device__ __forceinline__ float colp13(const float (*arr)[33], int h, int w) {
    float s = 0.f;
#pragma unroll
    for (int k = 0; k < 13; ++k) s += H0c[k] * arr[h + 3 + k][w];
    return s;
}

// ---------------- K2: forward DTCWT per (b,c), halo-padded LDS ----------------
__global__ __launch_bounds__(256) void k_fwd(const float* __restrict__ A,
                                             const float* __restrict__ wll,
                                             float* __restrict__ LL,
                                             float* __restrict__ HSr,
                                             float* __restrict__ HSi) {
    __shared__ float sx[32][52];    // col w' = -9..40 at index w'+9
    __shared__ float slo[50][33];   // row h' = -9..40 at index h'+9
    __shared__ float shi[50][33];
    int bc = blockIdx.x;
    int c = bc & 63;
    int tid = threadIdx.x;
    const float* ap = A + (size_t)bc * 1024;
#pragma unroll
    for (int r = 0; r < 4; ++r) {
        int p = r * 256 + tid;
        sx[p >> 5][(p & 31) + 9] = ap[p];
    }
    __syncthreads();
    // mirror column halo
    for (int i = tid; i < 576; i += 256) {
        int h = i / 18, j = i - (i / 18) * 18;
        int wp = (j < 9) ? (j - 9) : (23 + j);
        sx[h][wp + 9] = sx[h][refl32(wp) + 9];
    }
    __syncthreads();
    // row filters
#pragma unroll
    for (int r = 0; r < 4; ++r) {
        int p = r * 256 + tid;
        int h = p >> 5, w = p & 31;
        const float* xr = &sx[h][w + 9];
        float lo = 0.f, hi = 0.f;
#pragma unroll
        for (int k = 0; k < 13; ++k) lo += H0c[k] * xr[k - 6];
#pragma unroll
        for (int k = 0; k < 19; ++k) hi += H1c[k] * xr[k - 9];
        slo[h + 9][w] = lo;
        shi[h + 9][w] = hi;
    }
    __syncthreads();
    // mirror row halo
    for (int i = tid; i < 576; i += 256) {
        int j = i >> 5, w = i & 31;
        int hp = (j < 9) ? (j - 9) : (23 + j);
        int hs = refl32(hp);
        slo[hp + 9][w] = slo[hs + 9][w];
        shi[hp + 9][w] = shi[hs + 9][w];
    }
    __syncthreads();
    // LL
#pragma unroll
    for (int r = 0; r < 4; ++r) {
        int p = r * 256 + tid;
        int h = p >> 5, w = p & 31;
        float acc = 0.f;
#pragma unroll
        for (int k = 0; k < 13; ++k) acc += H0c[k] * slo[h + 3 + k][w];
        LL[(size_t)bc * 1024 + p] = acc * wll[c * 1024 + p];
    }
    // subbands
    {
        int p = tid;
        int i = p >> 4, j = p & 15;
        int h0 = 2 * i, w0 = 2 * j;
        size_t base = (size_t)bc * 1536 + p;
        float a, bb, cc, dd;
        a = colp19(slo, h0, w0); bb = colp19(slo, h0, w0 + 1);
        cc = colp19(slo, h0 + 1, w0); dd = colp19(slo, h0 + 1, w0 + 1);
        HSr[base + 0 * 256] = (a - dd) * ISQ2; HSi[base + 0 * 256] = (bb + cc) * ISQ2;
        HSr[base + 5 * 256] = (a + dd) * ISQ2; HSi[base + 5 * 256] = (bb - cc) * ISQ2;
        a = colp19(shi, h0, w0); bb = colp19(shi, h0, w0 + 1);
        cc = colp19(shi, h0 + 1, w0); dd = colp19(shi, h0 + 1, w0 + 1);
        HSr[base + 1 * 256] = (a - dd) * ISQ2; HSi[base + 1 * 256] = (bb + cc) * ISQ2;
        HSr[base + 4 * 256] = (a + dd) * ISQ2; HSi[base + 4 * 256] = (bb - cc) * ISQ2;
        a = colp13(shi, h0, w0); bb = colp13(shi, h0, w0 + 1);
        cc = colp13(shi, h0 + 1, w0); dd = colp13(shi, h0 + 1, w0 + 1);
        HSr[base + 2 * 256] = (a - dd) * ISQ2; HSi[base + 2 * 256] = (bb + cc) * ISQ2;
        HSr[base + 3 * 256] = (a + dd) * ISQ2; HSi[base + 3 * 256] = (bb - cc) * ISQ2;
    }
}

// ---------------- K3: complex block-diagonal MLP (token-per-lane, scalar weights) --
__global__ __launch_bounds__(256, 4) void k_mlp(float* __restrict__ HSr,
                                                float* __restrict__ HSi,
                                                const float* __restrict__ w1,
                                                const float* __restrict__ w2,
                                                const float* __restrict__ b1,
                                                const float* __restrict__ b2) {
    int tid = threadIdx.x;
    int b = blockIdx.x / 6;
    int o = blockIdx.x - b * 6;
    size_t base = ((size_t)b * 384 + o) * 256 + tid;
#pragma unroll 1
    for (int q = 0; q < 4; ++q) {
        float xr[16], xi[16];
#pragma unroll
        for (int d = 0; d < 16; ++d) {
            size_t gi = base + (size_t)(q * 16 + d) * 1536;
            xr[d] = HSr[gi];
            xi[d] = HSi[gi];
        }
        float r1[16], i1[16];
#pragma unroll 4
        for (int k = 0; k < 16; ++k) {
            float ar = b1[q * 16 + k];
            float ai = b1[64 + q * 16 + k];
#pragma unroll
            for (int d = 0; d < 16; ++d) {
                float wr = w1[q * 256 + d * 16 + k];
                float wi = w1[1024 + q * 256 + d * 16 + k];
                ar += xr[d] * wr - xi[d] * wi;
                ai += xr[d] * wi + xi[d] * wr;
            }
            r1[k] = fmaxf(ar, 0.f);
            i1[k] = fmaxf(ai, 0.f);
        }
#pragma unroll 4
        for (int k = 0; k < 16; ++k) {
            float ar = b2[q * 16 + k];
            float ai = b2[64 + q * 16 + k];
#pragma unroll
            for (int d = 0; d < 16; ++d) {
                float wr = w2[q * 256 + d * 16 + k];
                float wi = w2[1024 + q * 256 + d * 16 + k];
                ar += r1[d] * wr - i1[d] * wi;
                ai += r1[d] * wi + i1[d] * wr;
            }
            size_t gi = base + (size_t)(q * 16 + k) * 1536;
            HSr[gi] = ar;
            HSi[gi] = ai;
        }
    }
}

// ---------------- K4: inverse DTCWT per (b,c), halo-padded LDS ----------------
__global__ __launch_bounds__(256) void k_inv(const float* __restrict__ LL,
                                             const float* __restrict__ HSr,
                                             const float* __restrict__ HSi,
                                             float* __restrict__ Y) {
    __shared__ float sll[50][33], slh[50][33], shl[50][33], shh[50][33];
    __shared__ float slo[32][52], shi[32][52];
    int bc = blockIdx.x;
    int tid = threadIdx.x;
    const float* lp = LL + (size_t)bc * 1024;
#pragma unroll
    for (int r = 0; r < 4; ++r) {
        int p = r * 256 + tid;
        sll[(p >> 5) + 9][p & 31] = lp[p];
    }
    {
        int p = tid;
        int i = p >> 4, j = p & 15;
        int h0 = 2 * i + 9, w0 = 2 * j;
        size_t base = (size_t)bc * 1536 + p;
        float o0r = HSr[base + 0 * 256], o0i = HSi[base + 0 * 256];
        float o1r = HSr[base + 1 * 256], o1i = HSi[base + 1 * 256];
        float o2r = HSr[base + 2 * 256], o2i = HSi[base + 2 * 256];
        float o3r = HSr[base + 3 * 256], o3i = HSi[base + 3 * 256];
        float o4r = HSr[base + 4 * 256], o4i = HSi[base + 4 * 256];
        float o5r = HSr[base + 5 * 256], o5i = HSi[base + 5 * 256];
        slh[h0][w0] = (o0r + o5r) * ISQ2;
        slh[h0][w0 + 1] = (o0i + o5i) * ISQ2;
        slh[h0 + 1][w0] = (o0i - o5i) * ISQ2;
        slh[h0 + 1][w0 + 1] = (o5r - o0r) * ISQ2;
        shl[h0][w0] = (o2r + o3r) * ISQ2;
        shl[h0][w0 + 1] = (o2i + o3i) * ISQ2;
        shl[h0 + 1][w0] = (o2i - o3i) * ISQ2;
        shl[h0 + 1][w0 + 1] = (o3r - o2r) * ISQ2;
        shh[h0][w0] = (o1r + o4r) * ISQ2;
        shh[h0][w0 + 1] = (o1i + o4i) * ISQ2;
        shh[h0 + 1][w0] = (o1i - o4i) * ISQ2;
        shh[h0 + 1][w0 + 1] = (o4r - o1r) * ISQ2;
    }
    __syncthreads();
    // mirror row halos
    for (int i = tid; i < 576; i += 256) {
        int j = i >> 5, w = i & 31;
        int hp = (j < 9) ? (j - 9) : (23 + j);
        int hs = refl32(hp);
        sll[hp + 9][w] = sll[hs + 9][w];
        slh[hp + 9][w] = slh[hs + 9][w];
        shl[hp + 9][w] = shl[hs + 9][w];
        shh[hp + 9][w] = shh[hs + 9][w];
    }
    __syncthreads();
    // column synthesis filters
#pragma unroll
    for (int r = 0; r < 4; ++r) {
        int p = r * 256 + tid;
        int h = p >> 5, w = p & 31;
        float lo = 0.f, hi = 0.f;
#pragma unroll
        for (int k = 0; k < 19; ++k) {
            float g0 = (k & 1) ? H1c[k] : -H1c[k];
            lo += g0 * sll[h + k][w];
            hi += g0 * shl[h + k][w];
        }
#pragma unroll
        for (int k = 0; k < 13; ++k) {
            float g1 = (k & 1) ? H0c[k] : -H0c[k];
            lo += g1 * slh[h + 3 + k][w];
            hi += g1 * shh[h + 3 + k][w];
        }
        slo[h][w + 9] = lo;
        shi[h][w + 9] = hi;
    }
    __syncthreads();
    // mirror column halos
    for (int i = tid; i < 576; i += 256) {
        int h = i / 18, j = i - (i / 18) * 18;
        int wp = (j < 9) ? (j - 9) : (23 + j);
        int ws = refl32(wp);
        slo[h][wp + 9] = slo[h][ws + 9];
        shi[h][wp + 9] = shi[h][ws + 9];
    }
    __syncthreads();
    // row synthesis filters
#pragma unroll
    for (int r = 0; r < 4; ++r) {
        int p = r * 256 + tid;
        int h = p >> 5, w = p & 31;
        const float* lr = &slo[h][w + 9];
        const float* hr = &shi[h][w + 9];
        float y = 0.f;
#pragma unroll
        for (int k = 0; k < 19; ++k) {
            float g0 = (k & 1) ? H1c[k] : -H1c[k];
            y += g0 * lr[k - 9];
        }
#pragma unroll
        for (int k = 0; k < 13; ++k) {
            float g1 = (k & 1) ? H0c[k] : -H0c[k];
            y += g1 * hr[k - 6];
        }
        Y[(size_t)bc * 1024 + p] = y;
    }
}

// ---------------- K4b: X1 = x + Y^T -> d_out (B,N,C) ----------------
__global__ __launch_bounds__(256) void k_addt(const float* __restrict__ Y,
                                              const float* __restrict__ x,
                                              float* __restrict__ out) {
    __shared__ float sy[64][65];
    int b = blockIdx.x >> 4;
    int n0 = (blockIdx.x & 15) << 6;
    int tid = threadIdx.x;
#pragma unroll
    for (int rep = 0; rep < 16; ++rep) {
        int idx = rep * 256 + tid;
        int c = idx >> 6, i = idx & 63;
        sy[c][i] = Y[((size_t)(b * 64 + c)) * 1024 + n0 + i];
    }
    __syncthreads();
#pragma unroll
    for (int rep = 0; rep < 16; ++rep) {
        int idx = rep * 256 + tid;
        int i = idx >> 6, c = idx & 63;
        size_t gi = ((size_t)b * 1024 + n0 + i) * 64 + c;
        out[gi] = x[gi] + sy[c][i];
    }
}

// ---------------- K5: LN2 + lin1 + GELU -> H1 bf16 chunk-major ----------------
__global__ __launch_bounds__(256) void k_leff1(const float* __restrict__ X1,
                                               const float* __restrict__ g2,
                                               const float* __restrict__ be2,
                                               const float* __restrict__ W1,
                                               const float* __restrict__ B1,
                                               unsigned short* __restrict__ H1b) {
    __shared__ float xs[64][65];
    __shared__ float w1s[64][128];
    int tid = threadIdx.x;
    size_t tok0 = (size_t)blockIdx.x * 64;
    int bimg = blockIdx.x >> 4;
    int hw0 = (blockIdx.x & 15) << 6;
    {
        int tok = tid >> 2, part = tid & 3;
        const float4* xp = (const float4*)(X1 + (tok0 + tok) * 64 + part * 16);
        float4 v0 = xp[0], v1 = xp[1], v2 = xp[2], v3 = xp[3];
        float s = v0.x + v0.y + v0.z + v0.w + v1.x + v1.y + v1.z + v1.w +
                  v2.x + v2.y + v2.z + v2.w + v3.x + v3.y + v3.z + v3.w;
        float ss = v0.x * v0.x + v0.y * v0.y + v0.z * v0.z + v0.w * v0.w +
                   v1.x * v1.x + v1.y * v1.y + v1.z * v1.z + v1.w * v1.w +
                   v2.x * v2.x + v2.y * v2.y + v2.z * v2.z + v2.w * v2.w +
                   v3.x * v3.x + v3.y * v3.y + v3.z * v3.z + v3.w * v3.w;
        s += __shfl_xor(s, 1, 64);
        ss += __shfl_xor(ss, 1, 64);
        s += __shfl_xor(s, 2, 64);
        ss += __shfl_xor(ss, 2, 64);
        float m = s * (1.f / 64.f);
        float var = ss * (1.f / 64.f) - m * m;
        float rstd = rsqrtf(var + 1e-5f);
        float vv[16] = {v0.x, v0.y, v0.z, v0.w, v1.x, v1.y, v1.z, v1.w,
                        v2.x, v2.y, v2.z, v2.w, v3.x, v3.y, v3.z, v3.w};
#pragma unroll
        for (int i = 0; i < 16; ++i) {
            int d = part * 16 + i;
            xs[tok][d] = (vv[i] - m) * rstd * g2[d] + be2[d];
        }
    }
    int tg = tid >> 5, cg = tid & 31;
#pragma unroll 1
    for (int half = 0; half < 2; ++half) {
        __syncthreads();
        for (int i = 0; i < 32; ++i) {
            int idx = i * 256 + tid;
            int d = idx >> 7, c = idx & 127;
            w1s[d][c] = W1[d * 256 + half * 128 + c];
        }
        __syncthreads();
        float acc[8][4];
#pragma unroll
        for (int t = 0; t < 8; ++t)
#pragma unroll
            for (int j = 0; j < 4; ++j)
                acc[t][j] = B1[half * 128 + j * 32 + cg];
#pragma unroll 2
        for (int d = 0; d < 64; ++d) {
            float w0 = w1s[d][cg];
            float w1v = w1s[d][32 + cg];
            float w2v = w1s[d][64 + cg];
            float w3v = w1s[d][96 + cg];
#pragma unroll
            for (int t = 0; t < 8; ++t) {
                float xv = xs[tg * 8 + t][d];
                acc[t][0] += xv * w0;
                acc[t][1] += xv * w1v;
                acc[t][2] += xv * w2v;
                acc[t][3] += xv * w3v;
            }
        }
#pragma unroll
        for (int t = 0; t < 8; ++t) {
            int hw = hw0 + tg * 8 + t;
#pragma unroll
            for (int j = 0; j < 4; ++j) {
                size_t gi = (((size_t)bimg * 8 + half * 4 + j) * 1024 + hw) * 32 + cg;
                H1b[gi] = f2bf(gelu_exact(acc[t][j]));
            }
        }
    }
}

// ---------------- K5b: prep DWT (tap-major) + W2T bf16 ----------------
__global__ __launch_bounds__(256) void k_prep(const float* __restrict__ DW,
                                              const float* __restrict__ W2,
                                              float* __restrict__ DWT,
                                              unsigned short* __restrict__ W2T) {
    int gid = blockIdx.x * 256 + threadIdx.x;
    int stride = gridDim.x * 256;
    for (int i = gid; i < 2304; i += stride) {
        int hid = i / 9, t = i - hid * 9;
        DWT[t * 256 + hid] = DW[i];
    }
    for (int i = gid; i < 16384; i += stride) {
        int n = i >> 8, k = i & 255;
        W2T[i] = f2bf(W2[k * 64 + n]);
    }
}

__device__ __forceinline__ void tapfma(uint4 v, const float* wp8, float cv[8]) {
    f32x4 q0 = ((const f32x4*)wp8)[0];
    f32x4 q1 = ((const f32x4*)wp8)[1];
    cv[0] += bflo(v.x) * q0.x;
    cv[1] += bfhi(v.x) * q0.y;
    cv[2] += bflo(v.y) * q0.z;
    cv[3] += bfhi(v.y) * q0.w;
    cv[4] += bflo(v.z) * q1.x;
    cv[5] += bfhi(v.z) * q1.y;
    cv[6] += bflo(v.w) * q1.z;
    cv[7] += bfhi(v.w) * q1.w;
}

// ---------------- K6: fused dwconv3x3+GELU+lin2(MFMA)+bias+residual ----------
// Per-row named tap registers (no arrays -> no scratch); 3 loads in flight.
__global__ __launch_bounds__(256) void k_leff2m(const unsigned short* __restrict__ H1b,
                                                const float* __restrict__ DWT,
                                                const float* __restrict__ DB,
                                                const unsigned short* __restrict__ W2T,
                                                const float* __restrict__ B2,
                                                float* __restrict__ out) {
    int tid = threadIdx.x;
    int wid = tid >> 6, lane = tid & 63;
    int mt = blockIdx.x * 4 + wid;   // 0..16383
    int b = mt >> 6;
    int rem = mt & 63;
    int h = rem >> 1;                // image row (wave-uniform)
    int w0 = (rem & 1) << 4;         // 0 or 16
    int lr = lane & 15;              // A-row (token) / C-col index
    int kg = lane >> 4;              // k-group 0..3
    int wA = w0 + lr;                // this lane's token w

    f32x4 acc[4];
#pragma unroll
    for (int n = 0; n < 4; ++n) acc[n] = (f32x4){0.f, 0.f, 0.f, 0.f};

#pragma unroll 1
    for (int k0 = 0; k0 < 8; ++k0) {
        int hid0 = k0 * 32 + kg * 8;
        size_t cbase = ((size_t)b * 8 + k0) * 1024;
        const f32x4* dbp = (const f32x4*)(DB + hid0);
        f32x4 d0 = dbp[0], d1 = dbp[1];
        float cv[8] = {d0.x, d0.y, d0.z, d0.w, d1.x, d1.y, d1.z, d1.w};
#pragma unroll
        for (int dr = -1; dr <= 1; ++dr) {
            int hr = h + dr;
            if (hr < 0 || hr > 31) continue;   // wave-uniform branch
            size_t rb = (cbase + (size_t)hr * 32) << 5;
            uint4 t0 = make_uint4(0u, 0u, 0u, 0u);
            uint4 t2 = make_uint4(0u, 0u, 0u, 0u);
            uint4 t1 = *(const uint4*)(H1b + rb + ((size_t)wA << 5) + kg * 8);
            if (wA > 0) t0 = *(const uint4*)(H1b + rb + ((size_t)(wA - 1) << 5) + kg * 8);
            if (wA < 31) t2 = *(const uint4*)(H1b + rb + ((size_t)(wA + 1) << 5) + kg * 8);
            int tb = (dr + 1) * 3;
            tapfma(t0, DWT + (tb + 0) * 256 + hid0, cv);
            tapfma(t1, DWT + (tb + 1) * 256 + hid0, cv);
            tapfma(t2, DWT + (tb + 2) * 256 + hid0, cv);
        }
        bfrag8 a;
#pragma unroll
        for (int e = 0; e < 8; ++e) a[e] = (short)f2bf(gelu_exact(cv[e]));
#pragma unroll
        for (int n = 0; n < 4; ++n) {
            bfrag8 bf = *(const bfrag8*)(W2T + ((size_t)(n * 16 + lr) * 256 + k0 * 32 + kg * 8));
            acc[n] = __builtin_amdgcn_mfma_f32_16x16x32_bf16(a, bf, acc[n], 0, 0, 0);
        }
    }
    size_t obase = (size_t)b * 1024 + (size_t)h * 32;
#pragma unroll
    for (int n = 0; n < 4; ++n) {
        int c = n * 16 + lr;
        float b2v = B2[c];
#pragma unroll
        for (int reg = 0; reg < 4; ++reg) {
            int rowTok = w0 + kg * 4 + reg;
            size_t gi = (obase + rowTok) * 64 + c;
            out[gi] += acc[n][reg] + b2v;
        }
    }
}

extern "C" void kernel_launch(void* const* d_in, const int* in_sizes, int n_in,
                              void* d_out, int out_size, void* d_ws, size_t ws_size,
                              hipStream_t stream) {
    const float* x = (const float*)d_in[0];
    const float* ln1_g = (const float*)d_in[1];
    const float* ln1_b = (const float*)d_in[2];
    const float* w_ll = (const float*)d_in[3];
    const float* w1 = (const float*)d_in[4];
    const float* w2 = (const float*)d_in[5];
    const float* b1 = (const float*)d_in[6];
    const float* b2 = (const float*)d_in[7];
    const float* ln2_g = (const float*)d_in[8];
    const float* ln2_b = (const float*)d_in[9];
    const float* lin1_w = (const float*)d_in[10];
    const float* lin1_b = (const float*)d_in[11];
    const float* dw_w = (const float*)d_in[12];
    const float* dw_b = (const float*)d_in[13];
    const float* lin2_w = (const float*)d_in[14];
    const float* lin2_b = (const float*)d_in[15];
    float* out = (float*)d_out;
    char* ws = (char*)d_ws;

    float* A = (float*)ws;
    float* HSr = (float*)(ws + 67108864);
    float* HSi = (float*)(ws + 167772160);
    float* LL = out;
    float* Y = A;
    unsigned short* H1b = (unsigned short*)ws;          // [0, 134.2MB)
    float* DWT = (float*)(ws + 167772160);              // reuses dead HSi
    unsigned short* W2T = (unsigned short*)(ws + 167772160 + 16384);

    k_ln1_t<<<dim3(4096), dim3(256), 0, stream>>>(x, ln1_g, ln1_b, A);
    k_fwd<<<dim3(16384), dim3(256), 0, stream>>>(A, w_ll, LL, HSr, HSi);
    k_mlp<<<dim3(1536), dim3(256), 0, stream>>>(HSr, HSi, w1, w2, b1, b2);
    k_inv<<<dim3(16384), dim3(256), 0, stream>>>(LL, HSr, HSi, Y);
    k_addt<<<dim3(4096), dim3(256), 0, stream>>>(Y, x, out);
    k_prep<<<dim3(72), dim3(256), 0, stream>>>(dw_w, lin2_w, DWT, W2T);
    k_leff1<<<dim3(4096), dim3(256), 0, stream>>>(out, ln2_g, ln2_b, lin1_w, lin1_b, H1b);
    k_leff2m<<<dim3(4096), dim3(256), 0, stream>>>(H1b, DWT, dw_b, W2T, b2, out);
}

// Round 9
// 740.370 us; speedup vs baseline: 1.4228x; 1.1140x over previous
//
#include <hip/hip_runtime.h>
#include <math.h>

#define ISQ2 0.70710678118654752440f

typedef __attribute__((ext_vector_type(8))) short bfrag8;
typedef __attribute__((ext_vector_type(4))) float f32x4;

static __device__ __constant__ float H0c[13] = {
    -0.0017578f, 0.0f, 0.0222656f, -0.046875f, -0.0482422f, 0.296875f,
    0.5554688f, 0.296875f, -0.0482422f, -0.046875f, 0.0222656f, 0.0f, -0.0017578f};
static __device__ __constant__ float H1c[19] = {
    -7.06e-05f, 0.0f, 0.0013419f, -0.0018834f, -0.0071568f, 0.023856f,
    0.0556431f, -0.0516881f, -0.2997576f, 0.5594308f, -0.2997576f, -0.0516881f,
    0.0556431f, 0.023856f, -0.0071568f, -0.0018834f, 0.0013419f, 0.0f, -7.06e-05f};

__device__ __forceinline__ int refl32(int i) {
    if (i < 0) i = -1 - i;
    if (i > 31) i = 63 - i;
    return i;
}

// tanh-form GELU: |err| < ~1e-3 vs exact erf form, ~12 VALU ops
__device__ __forceinline__ float gelu_fast(float x) {
    float u = x * (0.7978845608f + 0.0356774081f * x * x);
    float e = __expf(-2.0f * fabsf(u));
    float t = 1.0f - 2.0f * e / (1.0f + e);
    t = copysignf(t, u);
    return 0.5f * x * (1.0f + t);
}

__device__ __forceinline__ float bf2f(unsigned short u) {
    union { unsigned int i; float f; } v;
    v.i = ((unsigned int)u) << 16;
    return v.f;
}

__device__ __forceinline__ float bflo(unsigned int u) {
    union { unsigned int i; float f; } v;
    v.i = u << 16;
    return v.f;
}
__device__ __forceinline__ float bfhi(unsigned int u) {
    union { unsigned int i; float f; } v;
    v.i = u & 0xFFFF0000u;
    return v.f;
}

__device__ __forceinline__ unsigned short f2bf(float a) {
    union { float f; unsigned int i; } ua;
    ua.f = a;
    unsigned int r = ua.i + 0x7FFF + ((ua.i >> 16) & 1);
    return (unsigned short)(r >> 16);
}

// ---------------- K1: LN1 + transpose (B,N,C)->(B,C,32,32) ----------------
__global__ __launch_bounds__(256) void k_ln1_t(const float* __restrict__ x,
                                               const float* __restrict__ g,
                                               const float* __restrict__ be,
                                               float* __restrict__ A) {
    __shared__ float sx[64][65];
    __shared__ float rs[64][4], rq[64][4];
    __shared__ float sm[64], sv[64];
    int b = blockIdx.x >> 4;
    int n0 = (blockIdx.x & 15) << 6;
    int tid = threadIdx.x;
    const float* xp = x + ((size_t)b * 1024 + n0) * 64;
#pragma unroll
    for (int rep = 0; rep < 16; ++rep) {
        int idx = rep * 256 + tid;
        sx[idx >> 6][idx & 63] = xp[idx];
    }
    __syncthreads();
    {
        int i = tid >> 2, q = tid & 3;
        float s = 0.f, ss = 0.f;
#pragma unroll
        for (int d = 0; d < 16; ++d) {
            float v = sx[i][q * 16 + d];
            s += v; ss += v * v;
        }
        rs[i][q] = s; rq[i][q] = ss;
    }
    __syncthreads();
    if (tid < 64) {
        float s = rs[tid][0] + rs[tid][1] + rs[tid][2] + rs[tid][3];
        float ss = rq[tid][0] + rq[tid][1] + rq[tid][2] + rq[tid][3];
        float m = s * (1.f / 64.f);
        float v = ss * (1.f / 64.f) - m * m;
        sm[tid] = m;
        sv[tid] = rsqrtf(v + 1e-5f);
    }
    __syncthreads();
#pragma unroll
    for (int rep = 0; rep < 16; ++rep) {
        int idx = rep * 256 + tid;
        int c = idx >> 6, i = idx & 63;
        float val = (sx[i][c] - sm[i]) * sv[i] * g[c] + be[c];
        A[((size_t)(b * 64 + c)) * 1024 + n0 + i] = val;
    }
}

// ---------------- K2: forward DTCWT, sliding-window register blocking ---------
// sx: padded cols (w+9), slo/shi: padded rows (h+9), stride 34 (8B-aligned rows)
__global__ __launch_bounds__(256, 4) void k_fwd(const float* __restrict__ A,
                                                const float* __restrict__ wll,
                                                float* __restrict__ LL,
                                                float* __restrict__ HSr,
                                                float* __restrict__ HSi) {
    __shared__ float sx[32][52];
    __shared__ float slo[50][34];
    __shared__ float shi[50][34];
    int bc = blockIdx.x;
    int c = bc & 63;
    int tid = threadIdx.x;
    int hA = tid >> 3, w0r = (tid & 7) * 4;
    {
        const float4* ap4 = (const float4*)(A + (size_t)bc * 1024);
        float4 v = ap4[tid];
        sx[hA][w0r + 9] = v.x;
        sx[hA][w0r + 10] = v.y;
        sx[hA][w0r + 11] = v.z;
        sx[hA][w0r + 12] = v.w;
    }
    __syncthreads();
    for (int i = tid; i < 576; i += 256) {
        int h = i / 18, j = i - (i / 18) * 18;
        int wp = (j < 9) ? (j - 9) : (23 + j);
        sx[h][wp + 9] = sx[h][refl32(wp) + 9];
    }
    __syncthreads();
    // row filters: 4 consecutive-w outputs per thread share a 22-float window
    {
        float ws[22];
#pragma unroll
        for (int t = 0; t < 22; ++t) ws[t] = sx[hA][w0r + t];
        float lo[4] = {0.f, 0.f, 0.f, 0.f}, hi[4] = {0.f, 0.f, 0.f, 0.f};
#pragma unroll
        for (int k = 0; k < 19; ++k)
#pragma unroll
            for (int j = 0; j < 4; ++j) hi[j] += H1c[k] * ws[j + k];
#pragma unroll
        for (int k = 0; k < 13; ++k)
#pragma unroll
            for (int j = 0; j < 4; ++j) lo[j] += H0c[k] * ws[j + k + 3];
#pragma unroll
        for (int j = 0; j < 4; ++j) {
            slo[hA + 9][w0r + j] = lo[j];
            shi[hA + 9][w0r + j] = hi[j];
        }
    }
    __syncthreads();
    for (int i = tid; i < 576; i += 256) {
        int j = i >> 5, w = i & 31;
        int hp = (j < 9) ? (j - 9) : (23 + j);
        int hs = refl32(hp);
        slo[hp + 9][w] = slo[hs + 9][w];
        shi[hp + 9][w] = shi[hs + 9][w];
    }
    __syncthreads();
    // LL: 4 consecutive-h outputs per thread share a 16-float column window
    {
        int wL = tid & 31, h0 = (tid >> 5) * 4;
        float cs[16];
#pragma unroll
        for (int t = 0; t < 16; ++t) cs[t] = slo[h0 + 3 + t][wL];
#pragma unroll
        for (int j = 0; j < 4; ++j) {
            float acc = 0.f;
#pragma unroll
            for (int k = 0; k < 13; ++k) acc += H0c[k] * cs[j + k];
            int p = (h0 + j) * 32 + wL;
            LL[(size_t)bc * 1024 + p] = acc * wll[c * 1024 + p];
        }
    }
    // subbands: one quad per thread, float2 column windows (b64)
    {
        int i = tid >> 4, j = tid & 15;
        size_t base = (size_t)bc * 1536 + tid;
        float a, bb, cc2, dd;
        {
            float2 sl[20];
#pragma unroll
            for (int t = 0; t < 20; ++t) sl[t] = *(const float2*)&slo[2 * i + t][2 * j];
            a = bb = cc2 = dd = 0.f;
#pragma unroll
            for (int k = 0; k < 19; ++k) {
                a += H1c[k] * sl[k].x;
                bb += H1c[k] * sl[k].y;
                cc2 += H1c[k] * sl[k + 1].x;
                dd += H1c[k] * sl[k + 1].y;
            }
            HSr[base + 0 * 256] = (a - dd) * ISQ2; HSi[base + 0 * 256] = (bb + cc2) * ISQ2;
            HSr[base + 5 * 256] = (a + dd) * ISQ2; HSi[base + 5 * 256] = (bb - cc2) * ISQ2;
        }
        {
            float2 sh[20];
#pragma unroll
            for (int t = 0; t < 20; ++t) sh[t] = *(const float2*)&shi[2 * i + t][2 * j];
            a = bb = cc2 = dd = 0.f;
#pragma unroll
            for (int k = 0; k < 19; ++k) {
                a += H1c[k] * sh[k].x;
                bb += H1c[k] * sh[k].y;
                cc2 += H1c[k] * sh[k + 1].x;
                dd += H1c[k] * sh[k + 1].y;
            }
            HSr[base + 1 * 256] = (a - dd) * ISQ2; HSi[base + 1 * 256] = (bb + cc2) * ISQ2;
            HSr[base + 4 * 256] = (a + dd) * ISQ2; HSi[base + 4 * 256] = (bb - cc2) * ISQ2;
            a = bb = cc2 = dd = 0.f;
#pragma unroll
            for (int k = 0; k < 13; ++k) {
                a += H0c[k] * sh[k + 3].x;
                bb += H0c[k] * sh[k + 3].y;
                cc2 += H0c[k] * sh[k + 4].x;
                dd += H0c[k] * sh[k + 4].y;
            }
            HSr[base + 2 * 256] = (a - dd) * ISQ2; HSi[base + 2 * 256] = (bb + cc2) * ISQ2;
            HSr[base + 3 * 256] = (a + dd) * ISQ2; HSi[base + 3 * 256] = (bb - cc2) * ISQ2;
        }
    }
}

// ---------------- K3: complex block-diagonal MLP (token-per-lane, scalar weights) --
__global__ __launch_bounds__(256, 4) void k_mlp(float* __restrict__ HSr,
                                                float* __restrict__ HSi,
                                                const float* __restrict__ w1,
                                                const float* __restrict__ w2,
                                                const float* __restrict__ b1,
                                                const float* __restrict__ b2) {
    int tid = threadIdx.x;
    int b = blockIdx.x / 6;
    int o = blockIdx.x - b * 6;
    size_t base = ((size_t)b * 384 + o) * 256 + tid;
#pragma unroll 1
    for (int q = 0; q < 4; ++q) {
        float xr[16], xi[16];
#pragma unroll
        for (int d = 0; d < 16; ++d) {
            size_t gi = base + (size_t)(q * 16 + d) * 1536;
            xr[d] = HSr[gi];
            xi[d] = HSi[gi];
        }
        float r1[16], i1[16];
#pragma unroll 4
        for (int k = 0; k < 16; ++k) {
            float ar = b1[q * 16 + k];
            float ai = b1[64 + q * 16 + k];
#pragma unroll
            for (int d = 0; d < 16; ++d) {
                float wr = w1[q * 256 + d * 16 + k];
                float wi = w1[1024 + q * 256 + d * 16 + k];
                ar += xr[d] * wr - xi[d] * wi;
                ai += xr[d] * wi + xi[d] * wr;
            }
            r1[k] = fmaxf(ar, 0.f);
            i1[k] = fmaxf(ai, 0.f);
        }
#pragma unroll 4
        for (int k = 0; k < 16; ++k) {
            float ar = b2[q * 16 + k];
            float ai = b2[64 + q * 16 + k];
#pragma unroll
            for (int d = 0; d < 16; ++d) {
                float wr = w2[q * 256 + d * 16 + k];
                float wi = w2[1024 + q * 256 + d * 16 + k];
                ar += r1[d] * wr - i1[d] * wi;
                ai += r1[d] * wi + i1[d] * wr;
            }
            size_t gi = base + (size_t)(q * 16 + k) * 1536;
            HSr[gi] = ar;
            HSi[gi] = ai;
        }
    }
}

// ---------------- K4: inverse DTCWT, sliding-window register blocking ---------
__global__ __launch_bounds__(256, 4) void k_inv(const float* __restrict__ LL,
                                                const float* __restrict__ HSr,
                                                const float* __restrict__ HSi,
                                                float* __restrict__ Y) {
    __shared__ float sll[50][34], slh[50][34], shl[50][34], shh[50][34];
    __shared__ float slo[32][52], shi[32][52];
    int bc = blockIdx.x;
    int tid = threadIdx.x;
    int hA = tid >> 3, w0r = (tid & 7) * 4;
    {
        const float4* lp4 = (const float4*)(LL + (size_t)bc * 1024);
        float4 v = lp4[tid];
        sll[hA + 9][w0r] = v.x;
        sll[hA + 9][w0r + 1] = v.y;
        sll[hA + 9][w0r + 2] = v.z;
        sll[hA + 9][w0r + 3] = v.w;
    }
    {
        int i = tid >> 4, j = tid & 15;
        int h0 = 2 * i + 9, w0 = 2 * j;
        size_t base = (size_t)bc * 1536 + tid;
        float o0r = HSr[base + 0 * 256], o0i = HSi[base + 0 * 256];
        float o1r = HSr[base + 1 * 256], o1i = HSi[base + 1 * 256];
        float o2r = HSr[base + 2 * 256], o2i = HSi[base + 2 * 256];
        float o3r = HSr[base + 3 * 256], o3i = HSi[base + 3 * 256];
        float o4r = HSr[base + 4 * 256], o4i = HSi[base + 4 * 256];
        float o5r = HSr[base + 5 * 256], o5i = HSi[base + 5 * 256];
        *(float2*)&slh[h0][w0] = make_float2((o0r + o5r) * ISQ2, (o0i + o5i) * ISQ2);
        *(float2*)&slh[h0 + 1][w0] = make_float2((o0i - o5i) * ISQ2, (o5r - o0r) * ISQ2);
        *(float2*)&shl[h0][w0] = make_float2((o2r + o3r) * ISQ2, (o2i + o3i) * ISQ2);
        *(float2*)&shl[h0 + 1][w0] = make_float2((o2i - o3i) * ISQ2, (o3r - o2r) * ISQ2);
        *(float2*)&shh[h0][w0] = make_float2((o1r + o4r) * ISQ2, (o1i + o4i) * ISQ2);
        *(float2*)&shh[h0 + 1][w0] = make_float2((o1i - o4i) * ISQ2, (o4r - o1r) * ISQ2);
    }
    __syncthreads();
    for (int i = tid; i < 576; i += 256) {
        int j = i >> 5, w = i & 31;
        int hp = (j < 9) ? (j - 9) : (23 + j);
        int hs = refl32(hp);
        sll[hp + 9][w] = sll[hs + 9][w];
        slh[hp + 9][w] = slh[hs + 9][w];
        shl[hp + 9][w] = shl[hs + 9][w];
        shh[hp + 9][w] = shh[hs + 9][w];
    }
    __syncthreads();
    // column synthesis: 4 consecutive-h outputs/thread, shared windows
    {
        int wL = tid & 31, h0 = (tid >> 5) * 4;
        float w19[22], w13[16];
        float lo[4] = {0.f, 0.f, 0.f, 0.f}, hi[4] = {0.f, 0.f, 0.f, 0.f};
#pragma unroll
        for (int t = 0; t < 22; ++t) w19[t] = sll[h0 + t][wL];
#pragma unroll
        for (int k = 0; k < 19; ++k) {
            float g0 = (k & 1) ? H1c[k] : -H1c[k];
#pragma unroll
            for (int j = 0; j < 4; ++j) lo[j] += g0 * w19[j + k];
        }
#pragma unroll
        for (int t = 0; t < 16; ++t) w13[t] = slh[h0 + 3 + t][wL];
#pragma unroll
        for (int k = 0; k < 13; ++k) {
            float g1 = (k & 1) ? H0c[k] : -H0c[k];
#pragma unroll
            for (int j = 0; j < 4; ++j) lo[j] += g1 * w13[j + k];
        }
#pragma unroll
        for (int t = 0; t < 22; ++t) w19[t] = shl[h0 + t][wL];
#pragma unroll
        for (int k = 0; k < 19; ++k) {
            float g0 = (k & 1) ? H1c[k] : -H1c[k];
#pragma unroll
            for (int j = 0; j < 4; ++j) hi[j] += g0 * w19[j + k];
        }
#pragma unroll
        for (int t = 0; t < 16; ++t) w13[t] = shh[h0 + 3 + t][wL];
#pragma unroll
        for (int k = 0; k < 13; ++k) {
            float g1 = (k & 1) ? H0c[k] : -H0c[k];
#pragma unroll
            for (int j = 0; j < 4; ++j) hi[j] += g1 * w13[j + k];
        }
#pragma unroll
        for (int j = 0; j < 4; ++j) {
            slo[h0 + j][wL + 9] = lo[j];
            shi[h0 + j][wL + 9] = hi[j];
        }
    }
    __syncthreads();
    for (int i = tid; i < 576; i += 256) {
        int h = i / 18, j = i - (i / 18) * 18;
        int wp = (j < 9) ? (j - 9) : (23 + j);
        int ws2 = refl32(wp);
        slo[h][wp + 9] = slo[h][ws2 + 9];
        shi[h][wp + 9] = shi[h][ws2 + 9];
    }
    __syncthreads();
    // row synthesis: 4 consecutive-w outputs/thread, shared windows
    {
        float rw[22], rh[16];
#pragma unroll
        for (int t = 0; t < 22; ++t) rw[t] = slo[hA][w0r + t];
#pragma unroll
        for (int t = 0; t < 16; ++t) rh[t] = shi[hA][w0r + 3 + t];
        float y[4] = {0.f, 0.f, 0.f, 0.f};
#pragma unroll
        for (int k = 0; k < 19; ++k) {
            float g0 = (k & 1) ? H1c[k] : -H1c[k];
#pragma unroll
            for (int j = 0; j < 4; ++j) y[j] += g0 * rw[j + k];
        }
#pragma unroll
        for (int k = 0; k < 13; ++k) {
            float g1 = (k & 1) ? H0c[k] : -H0c[k];
#pragma unroll
            for (int j = 0; j < 4; ++j) y[j] += g1 * rh[j + k];
        }
        *(float4*)(Y + (size_t)bc * 1024 + hA * 32 + w0r) = make_float4(y[0], y[1], y[2], y[3]);
    }
}

// ---------------- K4b: X1 = x + Y^T -> d_out (B,N,C) ----------------
__global__ __launch_bounds__(256) void k_addt(const float* __restrict__ Y,
                                              const float* __restrict__ x,
                                              float* __restrict__ out) {
    __shared__ float sy[64][65];
    int b = blockIdx.x >> 4;
    int n0 = (blockIdx.x & 15) << 6;
    int tid = threadIdx.x;
#pragma unroll
    for (int rep = 0; rep < 16; ++rep) {
        int idx = rep * 256 + tid;
        int c = idx >> 6, i = idx & 63;
        sy[c][i] = Y[((size_t)(b * 64 + c)) * 1024 + n0 + i];
    }
    __syncthreads();
#pragma unroll
    for (int rep = 0; rep < 16; ++rep) {
        int idx = rep * 256 + tid;
        int i = idx >> 6, c = idx & 63;
        size_t gi = ((size_t)b * 1024 + n0 + i) * 64 + c;
        out[gi] = x[gi] + sy[c][i];
    }
}

// ---------------- K5: LN2 + lin1 + GELU -> H1 bf16 chunk-major ----------------
__global__ __launch_bounds__(256) void k_leff1(const float* __restrict__ X1,
                                               const float* __restrict__ g2,
                                               const float* __restrict__ be2,
                                               const float* __restrict__ W1,
                                               const float* __restrict__ B1,
                                               unsigned short* __restrict__ H1b) {
    __shared__ float xs[64][65];
    __shared__ float w1s[64][128];
    int tid = threadIdx.x;
    size_t tok0 = (size_t)blockIdx.x * 64;
    int bimg = blockIdx.x >> 4;
    int hw0 = (blockIdx.x & 15) << 6;
    {
        int tok = tid >> 2, part = tid & 3;
        const float4* xp = (const float4*)(X1 + (tok0 + tok) * 64 + part * 16);
        float4 v0 = xp[0], v1 = xp[1], v2 = xp[2], v3 = xp[3];
        float s = v0.x + v0.y + v0.z + v0.w + v1.x + v1.y + v1.z + v1.w +
                  v2.x + v2.y + v2.z + v2.w + v3.x + v3.y + v3.z + v3.w;
        float ss = v0.x * v0.x + v0.y * v0.y + v0.z * v0.z + v0.w * v0.w +
                   v1.x * v1.x + v1.y * v1.y + v1.z * v1.z + v1.w * v1.w +
                   v2.x * v2.x + v2.y * v2.y + v2.z * v2.z + v2.w * v2.w +
                   v3.x * v3.x + v3.y * v3.y + v3.z * v3.z + v3.w * v3.w;
        s += __shfl_xor(s, 1, 64);
        ss += __shfl_xor(ss, 1, 64);
        s += __shfl_xor(s, 2, 64);
        ss += __shfl_xor(ss, 2, 64);
        float m = s * (1.f / 64.f);
        float var = ss * (1.f / 64.f) - m * m;
        float rstd = rsqrtf(var + 1e-5f);
        float vv[16] = {v0.x, v0.y, v0.z, v0.w, v1.x, v1.y, v1.z, v1.w,
                        v2.x, v2.y, v2.z, v2.w, v3.x, v3.y, v3.z, v3.w};
#pragma unroll
        for (int i = 0; i < 16; ++i) {
            int d = part * 16 + i;
            xs[tok][d] = (vv[i] - m) * rstd * g2[d] + be2[d];
        }
    }
    int tg = tid >> 5, cg = tid & 31;
#pragma unroll 1
    for (int half = 0; half < 2; ++half) {
        __syncthreads();
        for (int i = 0; i < 32; ++i) {
            int idx = i * 256 + tid;
            int d = idx >> 7, c = idx & 127;
            w1s[d][c] = W1[d * 256 + half * 128 + c];
        }
        __syncthreads();
        float acc[8][4];
#pragma unroll
        for (int t = 0; t < 8; ++t)
#pragma unroll
            for (int j = 0; j < 4; ++j)
                acc[t][j] = B1[half * 128 + j * 32 + cg];
#pragma unroll 2
        for (int d = 0; d < 64; ++d) {
            float w0 = w1s[d][cg];
            float w1v = w1s[d][32 + cg];
            float w2v = w1s[d][64 + cg];
            float w3v = w1s[d][96 + cg];
#pragma unroll
            for (int t = 0; t < 8; ++t) {
                float xv = xs[tg * 8 + t][d];
                acc[t][0] += xv * w0;
                acc[t][1] += xv * w1v;
                acc[t][2] += xv * w2v;
                acc[t][3] += xv * w3v;
            }
        }
#pragma unroll
        for (int t = 0; t < 8; ++t) {
            int hw = hw0 + tg * 8 + t;
#pragma unroll
            for (int j = 0; j < 4; ++j) {
                size_t gi = (((size_t)bimg * 8 + half * 4 + j) * 1024 + hw) * 32 + cg;
                H1b[gi] = f2bf(gelu_fast(acc[t][j]));
            }
        }
    }
}

// ---------------- K5b: prep DWT (tap-major) + W2T bf16 ----------------
__global__ __launch_bounds__(256) void k_prep(const float* __restrict__ DW,
                                              const float* __restrict__ W2,
                                              float* __restrict__ DWT,
                                              unsigned short* __restrict__ W2T) {
    int gid = blockIdx.x * 256 + threadIdx.x;
    int stride = gridDim.x * 256;
    for (int i = gid; i < 2304; i += stride) {
        int hid = i / 9, t = i - hid * 9;
        DWT[t * 256 + hid] = DW[i];
    }
    for (int i = gid; i < 16384; i += stride) {
        int n = i >> 8, k = i & 255;
        W2T[i] = f2bf(W2[k * 64 + n]);
    }
}

__device__ __forceinline__ void tapfma(uint4 v, const float* wp8, float cv[8]) {
    f32x4 q0 = ((const f32x4*)wp8)[0];
    f32x4 q1 = ((const f32x4*)wp8)[1];
    cv[0] += bflo(v.x) * q0.x;
    cv[1] += bfhi(v.x) * q0.y;
    cv[2] += bflo(v.y) * q0.z;
    cv[3] += bfhi(v.y) * q0.w;
    cv[4] += bflo(v.z) * q1.x;
    cv[5] += bfhi(v.z) * q1.y;
    cv[6] += bflo(v.w) * q1.z;
    cv[7] += bfhi(v.w) * q1.w;
}

// ---------------- K6: fused dwconv3x3+GELU+lin2(MFMA)+bias+residual ----------
__global__ __launch_bounds__(256) void k_leff2m(const unsigned short* __restrict__ H1b,
                                                const float* __restrict__ DWT,
                                                const float* __restrict__ DB,
                                                const unsigned short* __restrict__ W2T,
                                                const float* __restrict__ B2,
                                                float* __restrict__ out) {
    int tid = threadIdx.x;
    int wid = tid >> 6, lane = tid & 63;
    int mt = blockIdx.x * 4 + wid;   // 0..16383
    int b = mt >> 6;
    int rem = mt & 63;
    int h = rem >> 1;
    int w0 = (rem & 1) << 4;
    int lr = lane & 15;
    int kg = lane >> 4;
    int wA = w0 + lr;

    f32x4 acc[4];
#pragma unroll
    for (int n = 0; n < 4; ++n) acc[n] = (f32x4){0.f, 0.f, 0.f, 0.f};

#pragma unroll 1
    for (int k0 = 0; k0 < 8; ++k0) {
        int hid0 = k0 * 32 + kg * 8;
        size_t cbase = ((size_t)b * 8 + k0) * 1024;
        const f32x4* dbp = (const f32x4*)(DB + hid0);
        f32x4 d0 = dbp[0], d1 = dbp[1];
        float cv[8] = {d0.x, d0.y, d0.z, d0.w, d1.x, d1.y, d1.z, d1.w};
#pragma unroll
        for (int dr = -1; dr <= 1; ++dr) {
            int hr = h + dr;
            if (hr < 0 || hr > 31) continue;   // wave-uniform branch
            size_t rb = (cbase + (size_t)hr * 32) << 5;
            uint4 t0 = make_uint4(0u, 0u, 0u, 0u);
            uint4 t2 = make_uint4(0u, 0u, 0u, 0u);
            uint4 t1 = *(const uint4*)(H1b + rb + ((size_t)wA << 5) + kg * 8);
            if (wA > 0) t0 = *(const uint4*)(H1b + rb + ((size_t)(wA - 1) << 5) + kg * 8);
            if (wA < 31) t2 = *(const uint4*)(H1b + rb + ((size_t)(wA + 1) << 5) + kg * 8);
            int tb = (dr + 1) * 3;
            tapfma(t0, DWT + (tb + 0) * 256 + hid0, cv);
            tapfma(t1, DWT + (tb + 1) * 256 + hid0, cv);
            tapfma(t2, DWT + (tb + 2) * 256 + hid0, cv);
        }
        bfrag8 a;
#pragma unroll
        for (int e = 0; e < 8; ++e) a[e] = (short)f2bf(gelu_fast(cv[e]));
#pragma unroll
        for (int n = 0; n < 4; ++n) {
            bfrag8 bf = *(const bfrag8*)(W2T + ((size_t)(n * 16 + lr) * 256 + k0 * 32 + kg * 8));
            acc[n] = __builtin_amdgcn_mfma_f32_16x16x32_bf16(a, bf, acc[n], 0, 0, 0);
        }
    }
    size_t obase = (size_t)b * 1024 + (size_t)h * 32;
#pragma unroll
    for (int n = 0; n < 4; ++n) {
        int c = n * 16 + lr;
        float b2v = B2[c];
#pragma unroll
        for (int reg = 0; reg < 4; ++reg) {
            int rowTok = w0 + kg * 4 + reg;
            size_t gi = (obase + rowTok) * 64 + c;
            out[gi] += acc[n][reg] + b2v;
        }
    }
}

extern "C" void kernel_launch(void* const* d_in, const int* in_sizes, int n_in,
                              void* d_out, int out_size, void* d_ws, size_t ws_size,
                              hipStream_t stream) {
    const float* x = (const float*)d_in[0];
    const float* ln1_g = (const float*)d_in[1];
    const float* ln1_b = (const float*)d_in[2];
    const float* w_ll = (const float*)d_in[3];
    const float* w1 = (const float*)d_in[4];
    const float* w2 = (const float*)d_in[5];
    const float* b1 = (const float*)d_in[6];
    const float* b2 = (const float*)d_in[7];
    const float* ln2_g = (const float*)d_in[8];
    const float* ln2_b = (const float*)d_in[9];
    const float* lin1_w = (const float*)d_in[10];
    const float* lin1_b = (const float*)d_in[11];
    const float* dw_w = (const float*)d_in[12];
    const float* dw_b = (const float*)d_in[13];
    const float* lin2_w = (const float*)d_in[14];
    const float* lin2_b = (const float*)d_in[15];
    float* out = (float*)d_out;
    char* ws = (char*)d_ws;

    float* A = (float*)ws;
    float* HSr = (float*)(ws + 67108864);
    float* HSi = (float*)(ws + 167772160);
    float* LL = out;
    float* Y = A;
    unsigned short* H1b = (unsigned short*)ws;
    float* DWT = (float*)(ws + 167772160);
    unsigned short* W2T = (unsigned short*)(ws + 167772160 + 16384);

    k_ln1_t<<<dim3(4096), dim3(256), 0, stream>>>(x, ln1_g, ln1_b, A);
    k_fwd<<<dim3(16384), dim3(256), 0, stream>>>(A, w_ll, LL, HSr, HSi);
    k_mlp<<<dim3(1536), dim3(256), 0, stream>>>(HSr, HSi, w1, w2, b1, b2);
    k_inv<<<dim3(16384), dim3(256), 0, stream>>>(LL, HSr, HSi, Y);
    k_addt<<<dim3(4096), dim3(256), 0, stream>>>(Y, x, out);
    k_prep<<<dim3(72), dim3(256), 0, stream>>>(dw_w, lin2_w, DWT, W2T);
    k_leff1<<<dim3(4096), dim3(256), 0, stream>>>(out, ln2_g, ln2_b, lin1_w, lin1_b, H1b);
    k_leff2m<<<dim3(4096), dim3(256), 0, stream>>>(H1b, DWT, dw_b, W2T, b2, out);
}